// Round 2
// 1480.794 us; speedup vs baseline: 1.0970x; 1.0970x over previous
//
#include <hip/hip_runtime.h>
#include <cmath>

// ---------------------------------------------------------------------------
// PatchedQWenAttention: hidden -> QKV GEMM -> RoPE+logn -> paged KV gather ->
// flash attention -> out proj.  All matmuls in bf16 MFMA (16x16x32), fp32 acc.
//
// R4: race-free 256^2 8-phase GEMM.  R3 staged (t+2) halves into the live
// buffer before their last reads (A half0 staged P2, read P3; B half1 staged
// P3, read P4) -> LDS corruption.  Fix: read ALL B fragments at P1 (bR[4][2]),
// quadrant order (0,0),(0,1),(1,0),(1,1); stage at 64-row quarter granularity
// strictly after each slot's last-read phase barrier:
//   P2: stage (t+2).{Bq0,Bq1,Aq0}   (B,Aq0 last read P1)
//   P3: READ_A(1); stage (t+2).{Bq2,Bq3,Aq2}
//   P4: stage (t+2).{Aq1,Aq3} (last read P3); s_waitcnt vmcnt(8)
// 8 stage instrs/thread/tile; vmcnt(8) leaves exactly this tile's stages in
// flight and guarantees tile t+1 resident.  vmcnt(0) at the tail.
// ---------------------------------------------------------------------------

typedef unsigned short bfraw;
typedef __attribute__((ext_vector_type(8))) __bf16 bf16x8;
typedef __attribute__((ext_vector_type(4))) float f32x4;
typedef __attribute__((ext_vector_type(8))) unsigned short us8;

__device__ __forceinline__ bfraw f2bf(float f) {
  unsigned int u = __float_as_uint(f);
  u = (u + 0x7FFFu + ((u >> 16) & 1u)) >> 16;
  return (bfraw)u;
}
__device__ __forceinline__ float bf2f(bfraw h) {
  return __uint_as_float(((unsigned int)h) << 16);
}
__device__ __forceinline__ void gl_lds16(const void* g, void* l) {
  __builtin_amdgcn_global_load_lds(
      (const __attribute__((address_space(1))) unsigned int*)g,
      (__attribute__((address_space(3))) unsigned int*)l, 16, 0, 0);
}

// ---------------- fp32 -> bf16 convert (same layout) ----------------
__global__ __launch_bounds__(256) void cvt_kernel(const float* __restrict__ s,
                                                  bfraw* __restrict__ d, int n) {
  int i = (blockIdx.x * 256 + threadIdx.x) * 8;
  if (i >= n) return;
  float4 a = *(const float4*)(s + i);
  float4 b = *(const float4*)(s + i + 4);
  bfraw o[8] = {f2bf(a.x), f2bf(a.y), f2bf(a.z), f2bf(a.w),
                f2bf(b.x), f2bf(b.y), f2bf(b.z), f2bf(b.w)};
  *(us8*)(d + i) = *(const us8*)o;
}

// ---------------- fp32 [R][C] -> bf16 [C][R] tiled transpose ----------------
__global__ __launch_bounds__(256) void tconv_kernel(const float* __restrict__ src,
                                                    bfraw* __restrict__ dst,
                                                    int R, int C) {
  __shared__ float tile[32][33];
  int tx = threadIdx.x & 31, ty = threadIdx.x >> 5;  // ty 0..7
  int c0 = blockIdx.x * 32, r0 = blockIdx.y * 32;
#pragma unroll
  for (int p = 0; p < 4; ++p) {
    int r = p * 8 + ty;
    tile[r][tx] = src[(size_t)(r0 + r) * C + c0 + tx];
  }
  __syncthreads();
#pragma unroll
  for (int p = 0; p < 4; ++p) {
    int r = p * 8 + ty;
    dst[(size_t)(c0 + r) * R + r0 + tx] = f2bf(tile[tx][r]);
  }
}

// ---------------- 256^2 8-phase bf16 GEMM ----------------------------------
// C[M,N] = A[M,K] * Bt[N,K]^T.  512 thr = 8 waves (2 M x 4 N), BK=64,
// per-wave 128x64 output (acc[8][4]).  LDS 128 KiB double-buffered.
// Chunk swizzle: LDS chunk slot (row, p) holds global chunk p ^ (row & 7).
template <bool BIAS, bool OUT_BF16>
__global__ __launch_bounds__(512, 2) void gemm256(const bfraw* __restrict__ A,
                                                  const bfraw* __restrict__ Bt,
                                                  const float* __restrict__ bias,
                                                  void* __restrict__ Cout,
                                                  int M, int N, int K) {
  __shared__ __align__(16) bfraw As[2][16384];
  __shared__ __align__(16) bfraw Bs[2][16384];
  const int tid = threadIdx.x;
  const int lane = tid & 63;
  const int wid = tid >> 6;           // 0..7
  const int wm = wid >> 2;            // 0..1  (M row of wave)
  const int wn = wid & 3;             // 0..3  (N col of wave)
  const int quad = lane >> 4, l16 = lane & 15;

  // T1: bijective XCD swizzle on the flat block id (nwg % 8 == 0 for all uses)
  const int nwg = gridDim.x * gridDim.y;
  const int flat = blockIdx.y * gridDim.x + blockIdx.x;
  const int cpx = nwg >> 3;
  const int swz = (flat & 7) * cpx + (flat >> 3);
  const int bx = swz % gridDim.x, by = swz / gridDim.x;
  const int m0 = by * 256, n0 = bx * 256;

  const int NT = K >> 6;  // 64-wide K tiles

  // -------- staging addressing: 1 gl_lds16 per thread per 64-row quarter ----
  const int rr = tid >> 3;                       // row within quarter, 0..63
  const int cgl = ((tid & 7) ^ (rr & 7)) * 8;    // swizzled global chunk *8
  const size_t qgoff = (size_t)rr * K + cgl;     // quarter-relative global off
  const int ldsq = wid * 512;                    // wave-uniform LDS elem off

  // -------- fragment read addressing (elements) ----------------------------
  const int kx = l16 & 7;
  const int ck0 = ((0 + quad) ^ kx) * 8;    // kk=0 swizzled chunk offset
  const int ck1 = ((4 + quad) ^ kx) * 8;    // kk=1
  const int aBase = wm * 8192 + l16 * 64;
  const int bBase = (wn >> 1) * 8192 + ((wn & 1) * 64 + l16) * 64;

  f32x4 acc[8][4];
#pragma unroll
  for (int i = 0; i < 8; ++i)
#pragma unroll
    for (int j = 0; j < 4; ++j) acc[i][j] = {0.f, 0.f, 0.f, 0.f};

#define STAGE_A(tt, qq)                                                      \
  gl_lds16(A + (size_t)(m0 + (qq)*64) * K + (size_t)(tt)*64 + qgoff,         \
           &As[(tt) & 1][(qq)*4096 + ldsq])

#define STAGE_B(tt, qq)                                                      \
  gl_lds16(Bt + (size_t)(n0 + (qq)*64) * K + (size_t)(tt)*64 + qgoff,        \
           &Bs[(tt) & 1][(qq)*4096 + ldsq])

#define READ_A(QA)                                                \
  do {                                                            \
    _Pragma("unroll") for (int m4 = 0; m4 < 4; ++m4) {            \
      const bfraw* _p = &As[buf][aBase + ((QA)*4 + m4) * 1024];   \
      aR[m4][0] = *(const bf16x8*)(_p + ck0);                     \
      aR[m4][1] = *(const bf16x8*)(_p + ck1);                     \
    }                                                             \
  } while (0)

#define READ_B_ALL                                                \
  do {                                                            \
    _Pragma("unroll") for (int n2 = 0; n2 < 4; ++n2) {            \
      const bfraw* _p = &Bs[buf][bBase + n2 * 1024];              \
      bR[n2][0] = *(const bf16x8*)(_p + ck0);                     \
      bR[n2][1] = *(const bf16x8*)(_p + ck1);                     \
    }                                                             \
  } while (0)

#define MFMA16(QA, QB)                                                        \
  do {                                                                        \
    _Pragma("unroll") for (int m4 = 0; m4 < 4; ++m4)                          \
        _Pragma("unroll") for (int n2 = 0; n2 < 2; ++n2)                      \
            _Pragma("unroll") for (int kk = 0; kk < 2; ++kk)                  \
                acc[(QA)*4 + m4][(QB)*2 + n2] =                               \
        __builtin_amdgcn_mfma_f32_16x16x32_bf16(                              \
            aR[m4][kk], bR[(QB)*2 + n2][kk],                                  \
            acc[(QA)*4 + m4][(QB)*2 + n2], 0, 0, 0);                          \
  } while (0)

  // -------- prologue: stage tile 0 and tile 1 fully ------------------------
#pragma unroll
  for (int qq = 0; qq < 4; ++qq) {
    STAGE_A(0, qq);
    STAGE_B(0, qq);
  }
  if (NT > 1) {
#pragma unroll
    for (int qq = 0; qq < 4; ++qq) {
      STAGE_A(1, qq);
      STAGE_B(1, qq);
    }
    asm volatile("s_waitcnt vmcnt(8)" ::: "memory");
  } else {
    asm volatile("s_waitcnt vmcnt(0)" ::: "memory");
  }
  __builtin_amdgcn_s_barrier();

  bf16x8 aR[4][2], bR[4][2];
  for (int t = 0; t < NT; ++t) {
    const int buf = t & 1;
    const bool pf = (t + 2 < NT);
    // ---- P1: reads A(0) + all B; MFMA quadrant (0,0) ----
    READ_A(0);
    READ_B_ALL;
    __builtin_amdgcn_s_barrier();
    asm volatile("s_waitcnt lgkmcnt(0)" ::: "memory");
    __builtin_amdgcn_s_setprio(1);
    MFMA16(0, 0);
    __builtin_amdgcn_s_setprio(0);
    __builtin_amdgcn_s_barrier();
    // ---- P2: stage (t+2).{Bq0,Bq1,Aq0}; MFMA quadrant (0,1) ----
    if (pf) {
      STAGE_B(t + 2, 0);
      STAGE_B(t + 2, 1);
      STAGE_A(t + 2, 0);
    }
    __builtin_amdgcn_s_barrier();
    __builtin_amdgcn_s_setprio(1);
    MFMA16(0, 1);
    __builtin_amdgcn_s_setprio(0);
    __builtin_amdgcn_s_barrier();
    // ---- P3: reads A(1); stage (t+2).{Bq2,Bq3,Aq2}; MFMA quadrant (1,0) ----
    READ_A(1);
    if (pf) {
      STAGE_B(t + 2, 2);
      STAGE_B(t + 2, 3);
      STAGE_A(t + 2, 2);
    }
    __builtin_amdgcn_s_barrier();
    asm volatile("s_waitcnt lgkmcnt(0)" ::: "memory");
    __builtin_amdgcn_s_setprio(1);
    MFMA16(1, 0);
    __builtin_amdgcn_s_setprio(0);
    __builtin_amdgcn_s_barrier();
    // ---- P4: stage (t+2).{Aq1,Aq3}; counted vmcnt; MFMA quadrant (1,1) ----
    if (pf) {
      STAGE_A(t + 2, 1);
      STAGE_A(t + 2, 3);
      asm volatile("s_waitcnt vmcnt(8)" ::: "memory");
    } else {
      asm volatile("s_waitcnt vmcnt(0)" ::: "memory");
    }
    __builtin_amdgcn_s_barrier();
    __builtin_amdgcn_s_setprio(1);
    MFMA16(1, 1);
    __builtin_amdgcn_s_setprio(0);
    __builtin_amdgcn_s_barrier();
  }

#undef STAGE_A
#undef STAGE_B
#undef READ_A
#undef READ_B_ALL
#undef MFMA16

  // -------- epilogue -------------------------------------------------------
#pragma unroll
  for (int mi = 0; mi < 8; ++mi)
#pragma unroll
    for (int ni = 0; ni < 4; ++ni)
#pragma unroll
      for (int r = 0; r < 4; ++r) {
        int rowg = m0 + wm * 128 + mi * 16 + quad * 4 + r;
        int colg = n0 + wn * 64 + ni * 16 + l16;
        float v = acc[mi][ni][r];
        if (BIAS) v += bias[colg];
        if (OUT_BF16)
          ((bfraw*)Cout)[(size_t)rowg * N + colg] = f2bf(v);
        else
          ((float*)Cout)[(size_t)rowg * N + colg] = v;
      }
}

// ---------------- RoPE + logn*scale on q, RoPE on k (in place on qkv bf16) ---
__global__ __launch_bounds__(256) void rope_kernel(bfraw* __restrict__ qkv,
                                                   const float* __restrict__ cosb,
                                                   const float* __restrict__ sinb,
                                                   const int* __restrict__ pids) {
  int t = blockIdx.x, tid = threadIdx.x;
  bool is64 = (pids[1] == 0);  // int64 little-endian: high word of pids[0]==0
  int pos = is64 ? pids[2 * t] : pids[t];
  float pos1 = (float)(pos + 1);
  float logn = (pos + 1 > 1024) ? (logf(pos1) * 0.14426950408889634f /*1/ln(1024)*/)
                                : 1.0f;
  float qs = logn * 0.08838834764831845f;  // * 1/sqrt(128)
  const float* cr = cosb + (size_t)pos * 128;
  const float* sr = sinb + (size_t)pos * 128;
  for (int idx = tid; idx < 2048; idx += 256) {
    int h = idx >> 6, d = idx & 63;
    size_t base = (size_t)t * 12288 + h * 128 + d;
    float c0 = cr[d], s0 = sr[d], c1 = cr[d + 64], s1 = sr[d + 64];
    float x0 = bf2f(qkv[base]), x1 = bf2f(qkv[base + 64]);
    qkv[base] = f2bf((x0 * c0 - x1 * s0) * qs);
    qkv[base + 64] = f2bf((x1 * c1 + x0 * s1) * qs);
    float y0 = bf2f(qkv[base + 4096]), y1 = bf2f(qkv[base + 4096 + 64]);
    qkv[base + 4096] = f2bf(y0 * c0 - y1 * s0);
    qkv[base + 4096 + 64] = f2bf(y1 * c1 + y0 * s1);
  }
}

// ---------------- gather K: kfull[b,h,2048,128] bf16 -------------------------
__global__ __launch_bounds__(256) void build_k_kernel(const float* __restrict__ k_cache,
                                                      const bfraw* __restrict__ qkv,
                                                      const int* __restrict__ boff,
                                                      bfraw* __restrict__ kf) {
  int cid = blockIdx.x * 256 + threadIdx.x;  // 2^22 chunks of 8 elems
  int ch = (cid & 15) * 8;
  int kv = (cid >> 4) & 2047;
  int h = (cid >> 15) & 31;
  int b = cid >> 20;
  size_t o = ((size_t)(b * 32 + h) * 2048 + kv) * 128 + ch;
  if (kv < 1024) {
    int blk = boff[b * 32 + (kv >> 6)];
    const float* src = k_cache + (((size_t)(blk * 64 + (kv & 63)) * 32 + h) * 128 + ch);
    float4 a = *(const float4*)src;
    float4 c = *(const float4*)(src + 4);
    bfraw out8[8] = {f2bf(a.x), f2bf(a.y), f2bf(a.z), f2bf(a.w),
                     f2bf(c.x), f2bf(c.y), f2bf(c.z), f2bf(c.w)};
    *(us8*)&kf[o] = *(const us8*)out8;
  } else {
    const bfraw* src = qkv + (size_t)(b * 1024 + kv - 1024) * 12288 + 4096 + h * 128 + ch;
    *(us8*)&kf[o] = *(const us8*)src;
  }
}

// ---------------- gather+transpose V: vt[b,h,128,2048] bf16 ------------------
__global__ __launch_bounds__(256) void build_vt_kernel(const float* __restrict__ v_cache,
                                                       const bfraw* __restrict__ qkv,
                                                       const int* __restrict__ boff,
                                                       bfraw* __restrict__ vt) {
  __shared__ bfraw tile[64 * 136];  // [kv][dh], padded
  int bx = blockIdx.x;
  int kvt = bx & 31, bh = bx >> 5, b = bh >> 5, h = bh & 31;
  int kv0 = kvt * 64, tid = threadIdx.x;
#pragma unroll
  for (int i = 0; i < 4; ++i) {
    int cid = i * 256 + tid;
    int row = cid >> 4, ch = (cid & 15) * 8;
    int kv = kv0 + row;
    bfraw out8[8];
    if (kv < 1024) {
      int blk = boff[b * 32 + (kv >> 6)];
      const float* src = v_cache + (((size_t)(blk * 64 + (kv & 63)) * 32 + h) * 128 + ch);
      float4 a = *(const float4*)src;
      float4 c = *(const float4*)(src + 4);
      out8[0] = f2bf(a.x); out8[1] = f2bf(a.y); out8[2] = f2bf(a.z); out8[3] = f2bf(a.w);
      out8[4] = f2bf(c.x); out8[5] = f2bf(c.y); out8[6] = f2bf(c.z); out8[7] = f2bf(c.w);
    } else {
      const bfraw* src = qkv + (size_t)(b * 1024 + kv - 1024) * 12288 + 8192 + h * 128 + ch;
#pragma unroll
      for (int e = 0; e < 8; ++e) out8[e] = src[e];
    }
#pragma unroll
    for (int e = 0; e < 8; ++e) tile[row * 136 + ch + e] = out8[e];
  }
  __syncthreads();
  size_t obase = (size_t)bh * 128 * 2048 + kv0;
  for (int i = 0; i < 32; ++i) {
    int idx = i * 256 + tid;
    int dh = idx >> 6, c = idx & 63;
    vt[obase + (size_t)dh * 2048 + c] = tile[c * 136 + dh];
  }
}

// ---------------- flash attention ------------------------------------------
// grid (B*H, SQ/64), block 256 (4 waves); wave w owns q rows [w*16, w*16+16).
__global__ __launch_bounds__(256) void attn_kernel(const bfraw* __restrict__ qkv,
                                                   const bfraw* __restrict__ kf,
                                                   const bfraw* __restrict__ vt,
                                                   bfraw* __restrict__ attn) {
  __shared__ __align__(16) bfraw Qs[64 * 128];      // no pad (read once)
  __shared__ __align__(16) bfraw Ks[64 * 136];      // [kv][dh] pad->2-way
  __shared__ __align__(16) bfraw Vs[128 * 80];      // [dh][kv] pad (aligned)
  __shared__ __align__(16) bfraw Ps[4][16 * 80];    // per-wave P strip

  const int tid = threadIdx.x, lane = tid & 63, wid = tid >> 6;
  const int quad = lane >> 4, l16 = lane & 15;
  const int bh = blockIdx.x, b = bh >> 5, h = bh & 31;
  const int qt = blockIdx.y, q0 = qt * 64;

#pragma unroll
  for (int i = 0; i < 4; ++i) {
    int cid = i * 256 + tid;
    int row = cid >> 4, ch = (cid & 15) * 8;
    *(us8*)&Qs[row * 128 + ch] =
        *(const us8*)(qkv + (size_t)(b * 1024 + q0 + row) * 12288 + h * 128 + ch);
  }
  __syncthreads();
  bf16x8 aq[4];
#pragma unroll
  for (int kk = 0; kk < 4; ++kk)
    aq[kk] = *(const bf16x8*)&Qs[(wid * 16 + l16) * 128 + kk * 32 + quad * 8];

  f32x4 accO[8];
#pragma unroll
  for (int n2 = 0; n2 < 8; ++n2) accO[n2] = {0.f, 0.f, 0.f, 0.f};
  float mrun[4], lrun[4];
#pragma unroll
  for (int r = 0; r < 4; ++r) { mrun[r] = -3e38f; lrun[r] = 0.f; }

  const int ktiles = 17 + qt;
  const size_t kbase = (size_t)bh * 2048 * 128;
  const size_t vbase = (size_t)bh * 128 * 2048;

  for (int kt = 0; kt < ktiles; ++kt) {
    int kv0 = kt * 64;
    __syncthreads();  // protect Ks/Vs/Ps reuse
#pragma unroll
    for (int i = 0; i < 4; ++i) {
      int cid = i * 256 + tid;
      int row = cid >> 4, ch = (cid & 15) * 8;
      *(us8*)&Ks[row * 136 + ch] =
          *(const us8*)(kf + kbase + (size_t)(kv0 + row) * 128 + ch);
    }
#pragma unroll
    for (int i = 0; i < 4; ++i) {
      int cid = i * 256 + tid;
      int row = cid >> 3, ch = (cid & 7) * 8;
      *(us8*)&Vs[row * 80 + ch] =
          *(const us8*)(vt + vbase + (size_t)row * 2048 + kv0 + ch);
    }
    __syncthreads();

    // S = Q K^T  (16 rows x 64 cols per wave)
    f32x4 s[4];
#pragma unroll
    for (int j = 0; j < 4; ++j) {
      f32x4 c = {0.f, 0.f, 0.f, 0.f};
#pragma unroll
      for (int kk = 0; kk < 4; ++kk) {
        bf16x8 bk = *(const bf16x8*)&Ks[(j * 16 + l16) * 136 + kk * 32 + quad * 8];
        c = __builtin_amdgcn_mfma_f32_16x16x32_bf16(aq[kk], bk, c, 0, 0, 0);
      }
      s[j] = c;
    }
    if (kt == ktiles - 1) {  // triangular tile: kv0 == 1024+q0
#pragma unroll
      for (int j = 0; j < 4; ++j)
#pragma unroll
        for (int r = 0; r < 4; ++r) {
          int cc = j * 16 + l16;
          int rr = wid * 16 + quad * 4 + r;
          if (cc > rr) s[j][r] = -3e38f;
        }
    }
    // online softmax
#pragma unroll
    for (int r = 0; r < 4; ++r) {
      float mx = fmaxf(fmaxf(s[0][r], s[1][r]), fmaxf(s[2][r], s[3][r]));
#pragma unroll
      for (int o = 8; o >= 1; o >>= 1) mx = fmaxf(mx, __shfl_xor(mx, o, 64));
      float mnew = fmaxf(mrun[r], mx);
      float sum = 0.f;
#pragma unroll
      for (int j = 0; j < 4; ++j) {
        float p = __expf(s[j][r] - mnew);
        s[j][r] = p;
        sum += p;
      }
#pragma unroll
      for (int o = 8; o >= 1; o >>= 1) sum += __shfl_xor(sum, o, 64);
      float alpha = __expf(mrun[r] - mnew);
      lrun[r] = lrun[r] * alpha + sum;
      mrun[r] = mnew;
#pragma unroll
      for (int n2 = 0; n2 < 8; ++n2) accO[n2][r] *= alpha;
    }
    // P (C-layout) -> LDS -> A-layout
#pragma unroll
    for (int j = 0; j < 4; ++j)
#pragma unroll
      for (int r = 0; r < 4; ++r)
        Ps[wid][(quad * 4 + r) * 80 + j * 16 + l16] = f2bf(s[j][r]);
    __syncthreads();
    bf16x8 ap[2];
#pragma unroll
    for (int kk = 0; kk < 2; ++kk)
      ap[kk] = *(const bf16x8*)&Ps[wid][l16 * 80 + kk * 32 + quad * 8];
#pragma unroll
    for (int n2 = 0; n2 < 8; ++n2) {
#pragma unroll
      for (int kk = 0; kk < 2; ++kk) {
        bf16x8 bv = *(const bf16x8*)&Vs[(n2 * 16 + l16) * 80 + kk * 32 + quad * 8];
        accO[n2] = __builtin_amdgcn_mfma_f32_16x16x32_bf16(ap[kk], bv, accO[n2], 0, 0, 0);
      }
    }
  }
  // epilogue: O / l, write attn[t, h*128+dh]
#pragma unroll
  for (int r = 0; r < 4; ++r) {
    float inv = 1.0f / lrun[r];
    int t = b * 1024 + q0 + wid * 16 + quad * 4 + r;
#pragma unroll
    for (int n2 = 0; n2 < 8; ++n2)
      attn[(size_t)t * 4096 + h * 128 + n2 * 16 + l16] = f2bf(accO[n2][r] * inv);
  }
}

// ---------------------------------------------------------------------------
extern "C" void kernel_launch(void* const* d_in, const int* in_sizes, int n_in,
                              void* d_out, int out_size, void* d_ws, size_t ws_size,
                              hipStream_t stream) {
  const float* hidden = (const float*)d_in[0];
  const float* w_qkv = (const float*)d_in[1];
  const float* b_qkv = (const float*)d_in[2];
  const float* w_proj = (const float*)d_in[3];
  const float* cosb = (const float*)d_in[4];
  const float* sinb = (const float*)d_in[5];
  const float* k_cache = (const float*)d_in[6];
  const float* v_cache = (const float*)d_in[7];
  const int* boff = (const int*)d_in[8];
  const int* pids = (const int*)d_in[9];

  char* ws = (char*)d_ws;
  bfraw* hs = (bfraw*)(ws);                          // 33.5 MB (phase 1)
  bfraw* wqkv_t = (bfraw*)(ws + 33554432);           // 100.7 MB (phase 1)
  bfraw* kf = (bfraw*)(ws);                          // 67.1 MB (phase 2)
  bfraw* vt = (bfraw*)(ws + 67108864);               // 67.1 MB (phase 2)
  bfraw* qkv = (bfraw*)(ws + 134217728);             // 100.7 MB
  bfraw* wpj_t = (bfraw*)(ws + 234881024);           // 33.5 MB
  bfraw* attn = (bfraw*)(ws + 268435456);            // 33.5 MB  (total ~302 MB)

  cvt_kernel<<<8192, 256, 0, stream>>>(hidden, hs, 16777216);
  tconv_kernel<<<dim3(384, 128), 256, 0, stream>>>(w_qkv, wqkv_t, 4096, 12288);
  tconv_kernel<<<dim3(128, 128), 256, 0, stream>>>(w_proj, wpj_t, 4096, 4096);
  gemm256<true, true><<<dim3(48, 16), 512, 0, stream>>>(hs, wqkv_t, b_qkv, qkv,
                                                        4096, 12288, 4096);
  rope_kernel<<<4096, 256, 0, stream>>>(qkv, cosb, sinb, pids);
  build_k_kernel<<<16384, 256, 0, stream>>>(k_cache, qkv, boff, kf);
  build_vt_kernel<<<4096, 256, 0, stream>>>(v_cache, qkv, boff, vt);
  attn_kernel<<<dim3(128, 16), 256, 0, stream>>>(qkv, kf, vt, attn);
  gemm256<false, false><<<dim3(16, 16), 512, 0, stream>>>(attn, wpj_t, nullptr,
                                                          d_out, 4096, 4096, 4096);
}